// Round 11
// baseline (336.938 us; speedup 1.0000x reference)
//
#include <hip/hip_runtime.h>
#include <hip/hip_bf16.h>

// MoE top-2, T=32768 tokens, D=1024, E=8.
// Pipeline: gate(4 tok/wave) -> hist -> scan -> scatter(packed k-slot) -> wconv
//           -> grouped GEMM (128x256, 4 waves of 64x128, 32x32x16 MFMA, 3-buf ring,
//              vmcnt(6), 2 blk/CU) -> combine (bf16 partials -> fp32 out).

typedef __attribute__((ext_vector_type(8))) short short8_t;
typedef __attribute__((ext_vector_type(16))) float f32x16_t;
typedef __attribute__((ext_vector_type(4))) unsigned short us4_t;

#define GLOAD_LDS16(g, l)                                                                     \
  __builtin_amdgcn_global_load_lds((const __attribute__((address_space(1))) unsigned int*)(g), \
                                   (__attribute__((address_space(3))) unsigned int*)(l), 16, 0, 0)

__device__ __forceinline__ unsigned short f2bf(float f) {
  union { __hip_bfloat16 h; unsigned short u; } c;
  c.h = __float2bfloat16(f);
  return c.u;
}
__device__ __forceinline__ float bf2f(unsigned short u) {
  union { unsigned int i; float f; } c;
  c.i = ((unsigned int)u) << 16;
  return c.f;
}

// ---------------- gate: 4 tokens/wave; fp32 logits, top-2 softmax; x -> bf16 ----------------
__global__ __launch_bounds__(256) void gate_kernel(
    const float* __restrict__ x, const float* __restrict__ gw,
    unsigned short* __restrict__ xb,
    int* __restrict__ tok_e, float* __restrict__ tok_w)
{
  int wid = threadIdx.x >> 6, lane = threadIdx.x & 63;
  int t0 = (blockIdx.x << 4) + (wid << 2);              // 4 tokens per wave
  const float4* g4 = (const float4*)gw;                 // gw is [1024][8] row-major
  float lg[4][8] = {};
  #pragma unroll
  for (int c = 0; c < 4; ++c) {
    int d4 = (c << 6) + lane;                           // float4 index within a row
    float4 ga[4], gb[4];
    #pragma unroll
    for (int j = 0; j < 4; ++j) {
      int d = (d4 << 2) + j;
      ga[j] = g4[d << 1];
      gb[j] = g4[(d << 1) + 1];
    }
    #pragma unroll
    for (int t = 0; t < 4; ++t) {                       // reuse gw regs across 4 tokens
      const float4* x4 = (const float4*)(x + ((size_t)(t0 + t) << 10));
      float4 v = x4[d4];
      unsigned long long pk = (unsigned long long)f2bf(v.x)
                            | ((unsigned long long)f2bf(v.y) << 16)
                            | ((unsigned long long)f2bf(v.z) << 32)
                            | ((unsigned long long)f2bf(v.w) << 48);
      ((unsigned long long*)(xb + ((size_t)(t0 + t) << 10)))[d4] = pk;
      float xs[4] = {v.x, v.y, v.z, v.w};
      #pragma unroll
      for (int j = 0; j < 4; ++j) {
        lg[t][0] += xs[j]*ga[j].x; lg[t][1] += xs[j]*ga[j].y;
        lg[t][2] += xs[j]*ga[j].z; lg[t][3] += xs[j]*ga[j].w;
        lg[t][4] += xs[j]*gb[j].x; lg[t][5] += xs[j]*gb[j].y;
        lg[t][6] += xs[j]*gb[j].z; lg[t][7] += xs[j]*gb[j].w;
      }
    }
  }
  #pragma unroll
  for (int t = 0; t < 4; ++t)
    #pragma unroll
    for (int e = 0; e < 8; ++e) {
      float v = lg[t][e];
      #pragma unroll
      for (int s = 32; s > 0; s >>= 1) v += __shfl_xor(v, s, 64);
      lg[t][e] = v;
    }
  if (lane < 4) {                                       // lane t finalizes token t0+t
    int t = t0 + lane;
    float m0 = lg[lane][0], m1 = -3.4e38f; int e0 = 0, e1 = 0;
    #pragma unroll
    for (int e = 1; e < 8; ++e) {                       // strict '>' matches jax top_k ties
      float v = lg[lane][e];
      if (v > m0) { m1 = m0; e1 = e0; m0 = v; e0 = e; }
      else if (v > m1) { m1 = v; e1 = e; }
    }
    float p1 = 1.0f / (1.0f + expf(m0 - m1));
    float p0 = 1.0f - p1;
    int i0 = t << 1;
    tok_e[i0]   = e0; tok_w[i0]   = p0;
    tok_e[i0+1] = e1; tok_w[i0+1] = p1;
  }
}

// ---------------- hist: per-256-entry chunk, LDS histogram + local rank ----------------
__global__ __launch_bounds__(256) void hist_kernel(
    const int* __restrict__ tok_e, int* __restrict__ tok_r, int* __restrict__ chunkhist)
{
  __shared__ int lh[8];
  if (threadIdx.x < 8) lh[threadIdx.x] = 0;
  __syncthreads();
  int i = (blockIdx.x << 8) + threadIdx.x;
  int e = tok_e[i];
  tok_r[i] = atomicAdd(&lh[e], 1);
  __syncthreads();
  if (threadIdx.x < 8) chunkhist[(blockIdx.x << 3) + threadIdx.x] = lh[threadIdx.x];
}

// ---------------- scan: 8 waves, wave e scans expert e across 256 chunks ----------------
__global__ __launch_bounds__(512) void scan_kernel(
    const int* __restrict__ chunkhist, int* __restrict__ base, int* __restrict__ ctrl)
{
  __shared__ int h[2048];
  __shared__ int bx[2048];
  __shared__ int tot[8], eoff[8];
  for (int i = threadIdx.x; i < 2048; i += 512) h[i] = chunkhist[i];
  __syncthreads();
  int wid = threadIdx.x >> 6, lane = threadIdx.x & 63;
  int running = 0;
  #pragma unroll
  for (int b = 0; b < 4; ++b) {
    int c = (b << 6) + lane;
    int orig = h[(c << 3) + wid];
    int v = orig;
    #pragma unroll
    for (int s = 1; s < 64; s <<= 1) {
      int u = __shfl_up(v, s, 64);
      if (lane >= s) v += u;
    }
    bx[(c << 3) + wid] = running + v - orig;            // exclusive, expert-local
    running += __shfl(v, 63, 64);
  }
  if (lane == 0) tot[wid] = running;
  __syncthreads();
  if (threadIdx.x == 0) {
    int off = 0, boff = 0;
    #pragma unroll
    for (int e = 0; e < 8; ++e) {
      ctrl[e] = tot[e];
      ctrl[8 + e] = off; eoff[e] = off; off += tot[e];
      ctrl[16 + e] = boff; boff += (tot[e] + 127) >> 7;  // 128-row M-groups
    }
    ctrl[24] = boff;
  }
  __syncthreads();
  for (int i = threadIdx.x; i < 2048; i += 512) base[i] = bx[i] + eoff[i & 7];
}

// ---------------- scatter (t,k) -> dense slots; token + k-slot packed ----------------
__global__ __launch_bounds__(256) void scatter_kernel(
    const int* __restrict__ tok_e, const int* __restrict__ tok_r, const float* __restrict__ tok_w,
    const int* __restrict__ base, int* __restrict__ slot_token, float* __restrict__ slot_w)
{
  int i = (blockIdx.x << 8) + threadIdx.x;
  int e = tok_e[i];
  int slot = base[((i >> 8) << 3) + e] + tok_r[i];
  slot_token[slot] = (i >> 1) | ((i & 1) << 16);       // token | kslot<<16
  slot_w[slot] = tok_w[i];
}

// ---------------- expert_w fp32 [e][k][n] -> bf16 transposed Wt[e][n][k] ----------------
__global__ __launch_bounds__(256) void wconv_kernel(const float* __restrict__ w,
                                                    unsigned short* __restrict__ wt)
{
  __shared__ float tile[32][33];
  const float* we = w + ((size_t)blockIdx.z << 20);
  unsigned short* wte = wt + ((size_t)blockIdx.z << 20);
  int k0 = blockIdx.x << 5, n0 = blockIdx.y << 5;
  for (int i = threadIdx.x; i < 1024; i += 256) {
    int k = i >> 5, n = i & 31;
    tile[k][n] = we[(size_t)(k0 + k) * 1024 + n0 + n];
  }
  __syncthreads();
  for (int i = threadIdx.x; i < 1024; i += 256) {
    int n = i >> 5, k = i & 31;
    wte[(size_t)(n0 + n) * 1024 + k0 + k] = f2bf(tile[k][n]);
  }
}

// ---------------- grouped GEMM: 128x256 tile, 4 waves of 64x128, 32x32x16 MFMA ----------
// Sync structure identical to the measured-best r10 kernel (3-buf ring, 1 barrier/tile,
// vmcnt(6), 2-deep prefetch, 2 blocks/CU). MFMA shape widened to 32x32x16: 16 instrs/
// wave/tile instead of 32, ~20% fewer matrix-pipe busy cycles for the same FLOPs.
// A-frag: row=lane&31, 16B slot=2*ks+(lane>>5); same s^((row>>1)&3) both-sides swizzle
// (bank-tiling checked: 8 lanes x 16B per 4-bank quad -> conflict-free).
// C/D: col=lane&31, row=(reg&3)+8*(reg>>2)+4*(lane>>5)  [m74/m101].
__global__ __launch_bounds__(256, 2) void moe_gemm(
    const unsigned short* __restrict__ xb, const unsigned short* __restrict__ wt,
    const float* __restrict__ bias, const int* __restrict__ ctrl,
    const int* __restrict__ slot_token, const float* __restrict__ slot_w,
    unsigned short* __restrict__ part, float* __restrict__ out, int total_slots, int use_part)
{
  __shared__ unsigned short Alds[3 * 128 * 32];   // 24 KB: [buf][row][32k]
  __shared__ unsigned short Blds[3 * 256 * 32];   // 48 KB
  __shared__ int   tokid[128];
  __shared__ int   kslot[128];
  __shared__ float wrow[128];

  // dispatch map: 4 N-blocks of an M-group share one XCD (d&7)
  int d = blockIdx.x;
  int xcd = d & 7, nb = (d >> 3) & 3, gbase = d >> 5;
  int by = (gbase << 3) | xcd;                    // M-group id
  if (by >= ctrl[24]) return;
  int e = 0;
  #pragma unroll
  for (int i = 1; i < 8; ++i) if (by >= ctrl[16 + i]) e = i;
  int mblk = by - ctrl[16 + e];
  int cnt  = ctrl[e];
  int slot0 = ctrl[8 + e] + (mblk << 7);
  int rows_valid = cnt - (mblk << 7); if (rows_valid > 128) rows_valid = 128;

  int tid = threadIdx.x;
  if (tid < 128) {
    int s = slot0 + tid; if (s > total_slots - 1) s = total_slots - 1;
    int v = slot_token[s];
    tokid[tid] = v & 0xFFFF;
    kslot[tid] = v >> 16;
    wrow[tid]  = slot_w[s];
  }
  __syncthreads();

  int lane = tid & 63, w = tid >> 6;
  int wm = w >> 1, wn = w & 1;                    // wave grid 2x2; 64 rows x 128 cols/wave
  int l31 = lane & 31, h32 = lane >> 5;           // 32x32 fragment coords
  int bn0 = nb << 8;                              // 256-wide N-block
  const unsigned short* wte = wt + ((size_t)e << 20);

  // staging: 16B chunk c -> row c>>2, LDS slot c&3; src k-block (c&3)^((row>>1)&3).
  // A: 512 chunks (2/thread), B: 1024 chunks (4/thread).
  int rr = tid >> 2;                              // 0..63
  int kswz = (tid & 3) ^ ((tid >> 3) & 3);
  const unsigned short* gA0 = xb + ((size_t)tokid[rr] << 10) + (kswz << 3);
  const unsigned short* gA1 = xb + ((size_t)tokid[64 + rr] << 10) + (kswz << 3);
  const unsigned short* gB0 = wte + ((size_t)(bn0 + rr) << 10) + (kswz << 3);
  const unsigned short* gB1 = wte + ((size_t)(bn0 + 64 + rr) << 10) + (kswz << 3);
  const unsigned short* gB2 = wte + ((size_t)(bn0 + 128 + rr) << 10) + (kswz << 3);
  const unsigned short* gB3 = wte + ((size_t)(bn0 + 192 + rr) << 10) + (kswz << 3);
  int wbase = w << 9;                             // wave-uniform dest (shorts)

  f32x16_t acc[2][4] = {};

#define STAGE(NB, KO)                                                         \
  GLOAD_LDS16(gA0 + (KO), &Alds[(NB) * 4096 + wbase]);                        \
  GLOAD_LDS16(gA1 + (KO), &Alds[(NB) * 4096 + 2048 + wbase]);                 \
  GLOAD_LDS16(gB0 + (KO), &Blds[(NB) * 8192 + wbase]);                        \
  GLOAD_LDS16(gB1 + (KO), &Blds[(NB) * 8192 + 2048 + wbase]);                 \
  GLOAD_LDS16(gB2 + (KO), &Blds[(NB) * 8192 + 4096 + wbase]);                 \
  GLOAD_LDS16(gB3 + (KO), &Blds[(NB) * 8192 + 6144 + wbase]);

#define COMPUTE(BUF)                                                          \
  { short8_t aF[2][2], bF[4][2];                                              \
    _Pragma("unroll") for (int mt = 0; mt < 2; ++mt)                          \
    _Pragma("unroll") for (int ks = 0; ks < 2; ++ks) {                        \
      int ar = (wm << 6) + (mt << 5) + l31;                                   \
      int ps = ((ks << 1) + h32) ^ ((ar >> 1) & 3);                           \
      aF[mt][ks] = *(const short8_t*)&Alds[(BUF) * 4096 + (ar << 5) + (ps << 3)]; } \
    _Pragma("unroll") for (int nt = 0; nt < 4; ++nt)                          \
    _Pragma("unroll") for (int ks = 0; ks < 2; ++ks) {                        \
      int br = (wn << 7) + (nt << 5) + l31;                                   \
      int ps = ((ks << 1) + h32) ^ ((br >> 1) & 3);                           \
      bF[nt][ks] = *(const short8_t*)&Blds[(BUF) * 8192 + (br << 5) + (ps << 3)]; } \
    __builtin_amdgcn_s_setprio(1);                                            \
    _Pragma("unroll") for (int mt = 0; mt < 2; ++mt)                          \
    _Pragma("unroll") for (int nt = 0; nt < 4; ++nt)                          \
    _Pragma("unroll") for (int ks = 0; ks < 2; ++ks)                          \
      acc[mt][nt] = __builtin_amdgcn_mfma_f32_32x32x16_bf16(aF[mt][ks], bF[nt][ks], acc[mt][nt], 0, 0, 0); \
    __builtin_amdgcn_s_setprio(0); }

#define VM6 asm volatile("s_waitcnt vmcnt(6)" ::: "memory");
#define BARR __builtin_amdgcn_s_barrier();

  // prologue: stage tiles 0 -> buf0, 1 -> buf1; wait tile 0; barrier
  STAGE(0, 0)
  STAGE(1, 32)
  VM6
  BARR
  // main loop: tiles 0..29 (each stages t+2; vmcnt(6) retires t+1)
  for (int i = 0; i < 10; ++i) {
    int t = i * 3;
    STAGE(2, (t + 2) << 5)
    COMPUTE(0)
    VM6
    BARR
    STAGE(0, (t + 3) << 5)
    COMPUTE(1)
    VM6
    BARR
    STAGE(1, (t + 4) << 5)
    COMPUTE(2)
    VM6
    BARR
  }
  // tail: tile 30 (buf0; drain tile 31), tile 31 (buf1)
  COMPUTE(0)
  asm volatile("s_waitcnt vmcnt(0)" ::: "memory");
  BARR
  COMPUTE(1)
#undef STAGE
#undef COMPUTE
#undef VM6
#undef BARR

  const float* be = bias + (e << 10);
  float bv[4];
  #pragma unroll
  for (int nt = 0; nt < 4; ++nt) bv[nt] = be[bn0 + (wn << 7) + (nt << 5) + l31];
  #pragma unroll
  for (int mt = 0; mt < 2; ++mt) {
    #pragma unroll
    for (int r = 0; r < 16; ++r) {
      int row = (wm << 6) + (mt << 5) + (r & 3) + (((r >> 2)) << 3) + (h32 << 2);
      if (row < rows_valid) {
        float wv = wrow[row];
        if (use_part) {
          size_t obase = ((size_t)((tokid[row] << 1) | kslot[row]) << 10);
          #pragma unroll
          for (int nt = 0; nt < 4; ++nt) {
            int dout = bn0 + (wn << 7) + (nt << 5) + l31;
            part[obase + dout] = f2bf(wv * (acc[mt][nt][r] + bv[nt]));
          }
        } else {
          size_t obase = ((size_t)tokid[row] << 10);
          #pragma unroll
          for (int nt = 0; nt < 4; ++nt) {
            int dout = bn0 + (wn << 7) + (nt << 5) + l31;
            atomicAdd(&out[obase + dout], wv * (acc[mt][nt][r] + bv[nt]));
          }
        }
      }
    }
  }
}

// ---------------- combine: out[t][d] = part[t][0][d] + part[t][1][d] ----------------
__global__ __launch_bounds__(256) void combine_kernel(
    const unsigned short* __restrict__ part, float* __restrict__ out)
{
  int t = blockIdx.x, i = threadIdx.x;                 // 4 d's per thread
  const us4_t* p0 = (const us4_t*)(part + ((size_t)(t << 1) << 10));
  const us4_t* p1 = (const us4_t*)(part + ((size_t)((t << 1) | 1) << 10));
  us4_t a = p0[i], b = p1[i];
  float4 r;
  r.x = bf2f(a.x) + bf2f(b.x);
  r.y = bf2f(a.y) + bf2f(b.y);
  r.z = bf2f(a.z) + bf2f(b.z);
  r.w = bf2f(a.w) + bf2f(b.w);
  ((float4*)(out + ((size_t)t << 10)))[i] = r;
}

extern "C" void kernel_launch(void* const* d_in, const int* in_sizes, int n_in,
                              void* d_out, int out_size, void* d_ws, size_t ws_size,
                              hipStream_t stream) {
  (void)n_in;
  const float* x  = (const float*)d_in[0];
  const float* gw = (const float*)d_in[1];
  const float* ew = (const float*)d_in[2];
  const float* eb = (const float*)d_in[3];
  int T  = in_sizes[0] >> 10;   // 32768
  int T2 = T << 1;              // 65536 slots

  // workspace layout
  char* wsb = (char*)d_ws;
  unsigned short* xb = (unsigned short*)wsb;
  size_t off = (size_t)T * 1024 * 2;                    // x bf16: 64 MB
  unsigned short* wt = (unsigned short*)(wsb + off);
  off += (size_t)8 * 1024 * 1024 * 2;                   // Wt bf16: 16 MB
  int* ctrl = (int*)(wsb + off); off += 256;
  int* tok_e = (int*)(wsb + off); off += (size_t)T2 * 4;
  int* tok_r = (int*)(wsb + off); off += (size_t)T2 * 4;
  float* tok_w = (float*)(wsb + off); off += (size_t)T2 * 4;
  int* slot_token = (int*)(wsb + off); off += (size_t)T2 * 4;
  float* slot_w = (float*)(wsb + off); off += (size_t)T2 * 4;
  int* chunkhist = (int*)(wsb + off); off += 2048 * 4;
  int* base = (int*)(wsb + off); off += 2048 * 4;
  unsigned short* part = (unsigned short*)(wsb + off);
  size_t need = off + (size_t)T2 * 1024 * 2;            // +134 MB bf16 partials
  int use_part = (ws_size >= need) ? 1 : 0;

  float* out = (float*)d_out;

  if (!use_part)
    hipMemsetAsync(d_out, 0, (size_t)out_size * sizeof(float), stream);
  gate_kernel<<<T / 16, 256, 0, stream>>>(x, gw, xb, tok_e, tok_w);
  wconv_kernel<<<dim3(32, 32, 8), 256, 0, stream>>>(ew, wt);
  hist_kernel<<<T2 / 256, 256, 0, stream>>>(tok_e, tok_r, chunkhist);
  scan_kernel<<<1, 512, 0, stream>>>(chunkhist, base, ctrl);
  scatter_kernel<<<T2 / 256, 256, 0, stream>>>(tok_e, tok_r, tok_w, base,
                                               slot_token, slot_w);
  // up to 520 M-groups (128 rows) x 4 N-blocks (256 wide)
  moe_gemm<<<2080, 256, 0, stream>>>(xb, wt, eb, ctrl, slot_token, slot_w,
                                     part, out, T2, use_part);
  if (use_part)
    combine_kernel<<<T, 256, 0, stream>>>(part, out);
}

// Round 12
// 304.532 us; speedup vs baseline: 1.1064x; 1.1064x over previous
//
#include <hip/hip_runtime.h>
#include <hip/hip_bf16.h>

// MoE top-2, T=32768 tokens, D=1024, E=8.
// Pipeline: gate(4 tok/wave) -> hist -> scan -> scatter(packed k-slot) -> wconv
//           -> grouped GEMM (128x256, 4 waves of 64x128, 16x16x32 MFMA, 3-buf ring,
//              vmcnt(6), 2 blk/CU, read-before-stage phases) -> combine.

typedef __attribute__((ext_vector_type(8))) short short8_t;
typedef __attribute__((ext_vector_type(4))) float f32x4_t;
typedef __attribute__((ext_vector_type(4))) unsigned short us4_t;

#define GLOAD_LDS16(g, l)                                                                     \
  __builtin_amdgcn_global_load_lds((const __attribute__((address_space(1))) unsigned int*)(g), \
                                   (__attribute__((address_space(3))) unsigned int*)(l), 16, 0, 0)

__device__ __forceinline__ unsigned short f2bf(float f) {
  union { __hip_bfloat16 h; unsigned short u; } c;
  c.h = __float2bfloat16(f);
  return c.u;
}
__device__ __forceinline__ float bf2f(unsigned short u) {
  union { unsigned int i; float f; } c;
  c.i = ((unsigned int)u) << 16;
  return c.f;
}

// ---------------- gate: 4 tokens/wave; fp32 logits, top-2 softmax; x -> bf16 ----------------
__global__ __launch_bounds__(256) void gate_kernel(
    const float* __restrict__ x, const float* __restrict__ gw,
    unsigned short* __restrict__ xb,
    int* __restrict__ tok_e, float* __restrict__ tok_w)
{
  int wid = threadIdx.x >> 6, lane = threadIdx.x & 63;
  int t0 = (blockIdx.x << 4) + (wid << 2);              // 4 tokens per wave
  const float4* g4 = (const float4*)gw;                 // gw is [1024][8] row-major
  float lg[4][8] = {};
  #pragma unroll
  for (int c = 0; c < 4; ++c) {
    int d4 = (c << 6) + lane;                           // float4 index within a row
    float4 ga[4], gb[4];
    #pragma unroll
    for (int j = 0; j < 4; ++j) {
      int d = (d4 << 2) + j;
      ga[j] = g4[d << 1];
      gb[j] = g4[(d << 1) + 1];
    }
    #pragma unroll
    for (int t = 0; t < 4; ++t) {                       // reuse gw regs across 4 tokens
      const float4* x4 = (const float4*)(x + ((size_t)(t0 + t) << 10));
      float4 v = x4[d4];
      unsigned long long pk = (unsigned long long)f2bf(v.x)
                            | ((unsigned long long)f2bf(v.y) << 16)
                            | ((unsigned long long)f2bf(v.z) << 32)
                            | ((unsigned long long)f2bf(v.w) << 48);
      ((unsigned long long*)(xb + ((size_t)(t0 + t) << 10)))[d4] = pk;
      float xs[4] = {v.x, v.y, v.z, v.w};
      #pragma unroll
      for (int j = 0; j < 4; ++j) {
        lg[t][0] += xs[j]*ga[j].x; lg[t][1] += xs[j]*ga[j].y;
        lg[t][2] += xs[j]*ga[j].z; lg[t][3] += xs[j]*ga[j].w;
        lg[t][4] += xs[j]*gb[j].x; lg[t][5] += xs[j]*gb[j].y;
        lg[t][6] += xs[j]*gb[j].z; lg[t][7] += xs[j]*gb[j].w;
      }
    }
  }
  #pragma unroll
  for (int t = 0; t < 4; ++t)
    #pragma unroll
    for (int e = 0; e < 8; ++e) {
      float v = lg[t][e];
      #pragma unroll
      for (int s = 32; s > 0; s >>= 1) v += __shfl_xor(v, s, 64);
      lg[t][e] = v;
    }
  if (lane < 4) {                                       // lane t finalizes token t0+t
    int t = t0 + lane;
    float m0 = lg[lane][0], m1 = -3.4e38f; int e0 = 0, e1 = 0;
    #pragma unroll
    for (int e = 1; e < 8; ++e) {                       // strict '>' matches jax top_k ties
      float v = lg[lane][e];
      if (v > m0) { m1 = m0; e1 = e0; m0 = v; e0 = e; }
      else if (v > m1) { m1 = v; e1 = e; }
    }
    float p1 = 1.0f / (1.0f + expf(m0 - m1));
    float p0 = 1.0f - p1;
    int i0 = t << 1;
    tok_e[i0]   = e0; tok_w[i0]   = p0;
    tok_e[i0+1] = e1; tok_w[i0+1] = p1;
  }
}

// ---------------- hist: per-256-entry chunk, LDS histogram + local rank ----------------
__global__ __launch_bounds__(256) void hist_kernel(
    const int* __restrict__ tok_e, int* __restrict__ tok_r, int* __restrict__ chunkhist)
{
  __shared__ int lh[8];
  if (threadIdx.x < 8) lh[threadIdx.x] = 0;
  __syncthreads();
  int i = (blockIdx.x << 8) + threadIdx.x;
  int e = tok_e[i];
  tok_r[i] = atomicAdd(&lh[e], 1);
  __syncthreads();
  if (threadIdx.x < 8) chunkhist[(blockIdx.x << 3) + threadIdx.x] = lh[threadIdx.x];
}

// ---------------- scan: 8 waves, wave e scans expert e across 256 chunks ----------------
__global__ __launch_bounds__(512) void scan_kernel(
    const int* __restrict__ chunkhist, int* __restrict__ base, int* __restrict__ ctrl)
{
  __shared__ int h[2048];
  __shared__ int bx[2048];
  __shared__ int tot[8], eoff[8];
  for (int i = threadIdx.x; i < 2048; i += 512) h[i] = chunkhist[i];
  __syncthreads();
  int wid = threadIdx.x >> 6, lane = threadIdx.x & 63;
  int running = 0;
  #pragma unroll
  for (int b = 0; b < 4; ++b) {
    int c = (b << 6) + lane;
    int orig = h[(c << 3) + wid];
    int v = orig;
    #pragma unroll
    for (int s = 1; s < 64; s <<= 1) {
      int u = __shfl_up(v, s, 64);
      if (lane >= s) v += u;
    }
    bx[(c << 3) + wid] = running + v - orig;            // exclusive, expert-local
    running += __shfl(v, 63, 64);
  }
  if (lane == 0) tot[wid] = running;
  __syncthreads();
  if (threadIdx.x == 0) {
    int off = 0, boff = 0;
    #pragma unroll
    for (int e = 0; e < 8; ++e) {
      ctrl[e] = tot[e];
      ctrl[8 + e] = off; eoff[e] = off; off += tot[e];
      ctrl[16 + e] = boff; boff += (tot[e] + 127) >> 7;  // 128-row M-groups
    }
    ctrl[24] = boff;
  }
  __syncthreads();
  for (int i = threadIdx.x; i < 2048; i += 512) base[i] = bx[i] + eoff[i & 7];
}

// ---------------- scatter (t,k) -> dense slots; token + k-slot packed ----------------
__global__ __launch_bounds__(256) void scatter_kernel(
    const int* __restrict__ tok_e, const int* __restrict__ tok_r, const float* __restrict__ tok_w,
    const int* __restrict__ base, int* __restrict__ slot_token, float* __restrict__ slot_w)
{
  int i = (blockIdx.x << 8) + threadIdx.x;
  int e = tok_e[i];
  int slot = base[((i >> 8) << 3) + e] + tok_r[i];
  slot_token[slot] = (i >> 1) | ((i & 1) << 16);       // token | kslot<<16
  slot_w[slot] = tok_w[i];
}

// ---------------- expert_w fp32 [e][k][n] -> bf16 transposed Wt[e][n][k] ----------------
__global__ __launch_bounds__(256) void wconv_kernel(const float* __restrict__ w,
                                                    unsigned short* __restrict__ wt)
{
  __shared__ float tile[32][33];
  const float* we = w + ((size_t)blockIdx.z << 20);
  unsigned short* wte = wt + ((size_t)blockIdx.z << 20);
  int k0 = blockIdx.x << 5, n0 = blockIdx.y << 5;
  for (int i = threadIdx.x; i < 1024; i += 256) {
    int k = i >> 5, n = i & 31;
    tile[k][n] = we[(size_t)(k0 + k) * 1024 + n0 + n];
  }
  __syncthreads();
  for (int i = threadIdx.x; i < 1024; i += 256) {
    int n = i >> 5, k = i & 31;
    wte[(size_t)(n0 + n) * 1024 + k0 + k] = f2bf(tile[k][n]);
  }
}

// ---------------- grouped GEMM: 128x256 tile, 4 waves of 64x128, BK=32, 3-buf ring ----
// r10 structure (measured best: 188us, MfmaUtil 31.5%, 0 conflicts) with one change:
// per tile the ds_read frags issue BEFORE the 6 global_load_lds (LDS latency drains
// under the VMEM issue burst), MFMA cluster after. vmcnt(6) accounting unchanged.
// 16x16x32 MFMA; l15-row/hk-slot reads with s^((r>>1)&3) both-sides swizzle (the
// pattern measured conflict-free; the 32x32 l31/h32 variant measured 12.7M conflicts).
__global__ __launch_bounds__(256, 2) void moe_gemm(
    const unsigned short* __restrict__ xb, const unsigned short* __restrict__ wt,
    const float* __restrict__ bias, const int* __restrict__ ctrl,
    const int* __restrict__ slot_token, const float* __restrict__ slot_w,
    unsigned short* __restrict__ part, float* __restrict__ out, int total_slots, int use_part)
{
  __shared__ unsigned short Alds[3 * 128 * 32];   // 24 KB: [buf][row][32k]
  __shared__ unsigned short Blds[3 * 256 * 32];   // 48 KB
  __shared__ int   tokid[128];
  __shared__ int   kslot[128];
  __shared__ float wrow[128];

  // dispatch map: 4 N-blocks of an M-group share one XCD (d&7)
  int d = blockIdx.x;
  int xcd = d & 7, nb = (d >> 3) & 3, gbase = d >> 5;
  int by = (gbase << 3) | xcd;                    // M-group id
  if (by >= ctrl[24]) return;
  int e = 0;
  #pragma unroll
  for (int i = 1; i < 8; ++i) if (by >= ctrl[16 + i]) e = i;
  int mblk = by - ctrl[16 + e];
  int cnt  = ctrl[e];
  int slot0 = ctrl[8 + e] + (mblk << 7);
  int rows_valid = cnt - (mblk << 7); if (rows_valid > 128) rows_valid = 128;

  int tid = threadIdx.x;
  if (tid < 128) {
    int s = slot0 + tid; if (s > total_slots - 1) s = total_slots - 1;
    int v = slot_token[s];
    tokid[tid] = v & 0xFFFF;
    kslot[tid] = v >> 16;
    wrow[tid]  = slot_w[s];
  }
  __syncthreads();

  int lane = tid & 63, w = tid >> 6;
  int wm = w >> 1, wn = w & 1;                    // wave grid 2x2; 64 rows x 128 cols/wave
  int l15 = lane & 15, hk = lane >> 4;
  int bn0 = nb << 8;                              // 256-wide N-block
  const unsigned short* wte = wt + ((size_t)e << 20);

  // staging: 16B chunk c -> row c>>2, LDS slot c&3; src k-block (c&3)^((row>>1)&3).
  // A: 512 chunks (2/thread), B: 1024 chunks (4/thread).
  int rr = tid >> 2;                              // 0..63
  int kswz = (tid & 3) ^ ((tid >> 3) & 3);
  const unsigned short* gA0 = xb + ((size_t)tokid[rr] << 10) + (kswz << 3);
  const unsigned short* gA1 = xb + ((size_t)tokid[64 + rr] << 10) + (kswz << 3);
  const unsigned short* gB0 = wte + ((size_t)(bn0 + rr) << 10) + (kswz << 3);
  const unsigned short* gB1 = wte + ((size_t)(bn0 + 64 + rr) << 10) + (kswz << 3);
  const unsigned short* gB2 = wte + ((size_t)(bn0 + 128 + rr) << 10) + (kswz << 3);
  const unsigned short* gB3 = wte + ((size_t)(bn0 + 192 + rr) << 10) + (kswz << 3);
  int wbase = w << 9;                             // wave-uniform dest (shorts)

  f32x4_t acc[4][8] = {};

#define STAGE(NB, KO)                                                         \
  GLOAD_LDS16(gA0 + (KO), &Alds[(NB) * 4096 + wbase]);                        \
  GLOAD_LDS16(gA1 + (KO), &Alds[(NB) * 4096 + 2048 + wbase]);                 \
  GLOAD_LDS16(gB0 + (KO), &Blds[(NB) * 8192 + wbase]);                        \
  GLOAD_LDS16(gB1 + (KO), &Blds[(NB) * 8192 + 2048 + wbase]);                 \
  GLOAD_LDS16(gB2 + (KO), &Blds[(NB) * 8192 + 4096 + wbase]);                 \
  GLOAD_LDS16(gB3 + (KO), &Blds[(NB) * 8192 + 6144 + wbase]);

// per-tile phase: ds_read frags FIRST, then stage t+2, then MFMA cluster
#define TILE(BUF, PF, NB2, KO2)                                               \
  { short8_t aF[4], bF[8];                                                    \
    _Pragma("unroll") for (int m = 0; m < 4; ++m) {                           \
      int ar = (wm << 6) + (m << 4) + l15;                                    \
      aF[m] = *(const short8_t*)&Alds[(BUF) * 4096 + (ar << 5) + ((hk ^ ((ar >> 1) & 3)) << 3)]; } \
    _Pragma("unroll") for (int n = 0; n < 8; ++n) {                           \
      int br = (wn << 7) + (n << 4) + l15;                                    \
      bF[n] = *(const short8_t*)&Blds[(BUF) * 8192 + (br << 5) + ((hk ^ ((br >> 1) & 3)) << 3)]; } \
    if (PF) { STAGE(NB2, KO2) }                                               \
    __builtin_amdgcn_s_setprio(1);                                            \
    _Pragma("unroll") for (int m = 0; m < 4; ++m)                             \
    _Pragma("unroll") for (int n = 0; n < 8; ++n)                             \
      acc[m][n] = __builtin_amdgcn_mfma_f32_16x16x32_bf16(aF[m], bF[n], acc[m][n], 0, 0, 0); \
    __builtin_amdgcn_s_setprio(0); }

#define VM6 asm volatile("s_waitcnt vmcnt(6)" ::: "memory");
#define BARR __builtin_amdgcn_s_barrier();

  // prologue: stage tiles 0 -> buf0, 1 -> buf1; wait tile 0; barrier
  STAGE(0, 0)
  STAGE(1, 32)
  VM6
  BARR
  // main loop: tiles 0..29 (each stages t+2; vmcnt(6) retires t+1)
  for (int i = 0; i < 10; ++i) {
    int t = i * 3;
    TILE(0, 1, 2, (t + 2) << 5)
    VM6
    BARR
    TILE(1, 1, 0, (t + 3) << 5)
    VM6
    BARR
    TILE(2, 1, 1, (t + 4) << 5)
    VM6
    BARR
  }
  // tail: tile 30 (buf0; drain tile 31), tile 31 (buf1)
  TILE(0, 0, 0, 0)
  asm volatile("s_waitcnt vmcnt(0)" ::: "memory");
  BARR
  TILE(1, 0, 0, 0)
#undef STAGE
#undef TILE
#undef VM6
#undef BARR

  const float* be = bias + (e << 10);
  float bv[8];
  #pragma unroll
  for (int nf = 0; nf < 8; ++nf) bv[nf] = be[bn0 + (wn << 7) + (nf << 4) + l15];
  #pragma unroll
  for (int mf = 0; mf < 4; ++mf) {
    int rbase = (wm << 6) + (mf << 4) + (hk << 2);
    #pragma unroll
    for (int r = 0; r < 4; ++r) {
      int row = rbase + r;
      if (row < rows_valid) {
        float wv = wrow[row];
        if (use_part) {
          size_t obase = ((size_t)((tokid[row] << 1) | kslot[row]) << 10);
          #pragma unroll
          for (int nf = 0; nf < 8; ++nf) {
            int dout = bn0 + (wn << 7) + (nf << 4) + l15;
            part[obase + dout] = f2bf(wv * (acc[mf][nf][r] + bv[nf]));
          }
        } else {
          size_t obase = ((size_t)tokid[row] << 10);
          #pragma unroll
          for (int nf = 0; nf < 8; ++nf) {
            int dout = bn0 + (wn << 7) + (nf << 4) + l15;
            atomicAdd(&out[obase + dout], wv * (acc[mf][nf][r] + bv[nf]));
          }
        }
      }
    }
  }
}

// ---------------- combine: out[t][d] = part[t][0][d] + part[t][1][d] ----------------
__global__ __launch_bounds__(256) void combine_kernel(
    const unsigned short* __restrict__ part, float* __restrict__ out)
{
  int t = blockIdx.x, i = threadIdx.x;                 // 4 d's per thread
  const us4_t* p0 = (const us4_t*)(part + ((size_t)(t << 1) << 10));
  const us4_t* p1 = (const us4_t*)(part + ((size_t)((t << 1) | 1) << 10));
  us4_t a = p0[i], b = p1[i];
  float4 r;
  r.x = bf2f(a.x) + bf2f(b.x);
  r.y = bf2f(a.y) + bf2f(b.y);
  r.z = bf2f(a.z) + bf2f(b.z);
  r.w = bf2f(a.w) + bf2f(b.w);
  ((float4*)(out + ((size_t)t << 10)))[i] = r;
}

extern "C" void kernel_launch(void* const* d_in, const int* in_sizes, int n_in,
                              void* d_out, int out_size, void* d_ws, size_t ws_size,
                              hipStream_t stream) {
  (void)n_in;
  const float* x  = (const float*)d_in[0];
  const float* gw = (const float*)d_in[1];
  const float* ew = (const float*)d_in[2];
  const float* eb = (const float*)d_in[3];
  int T  = in_sizes[0] >> 10;   // 32768
  int T2 = T << 1;              // 65536 slots

  // workspace layout
  char* wsb = (char*)d_ws;
  unsigned short* xb = (unsigned short*)wsb;
  size_t off = (size_t)T * 1024 * 2;                    // x bf16: 64 MB
  unsigned short* wt = (unsigned short*)(wsb + off);
  off += (size_t)8 * 1024 * 1024 * 2;                   // Wt bf16: 16 MB
  int* ctrl = (int*)(wsb + off); off += 256;
  int* tok_e = (int*)(wsb + off); off += (size_t)T2 * 4;
  int* tok_r = (int*)(wsb + off); off += (size_t)T2 * 4;
  float* tok_w = (float*)(wsb + off); off += (size_t)T2 * 4;
  int* slot_token = (int*)(wsb + off); off += (size_t)T2 * 4;
  float* slot_w = (float*)(wsb + off); off += (size_t)T2 * 4;
  int* chunkhist = (int*)(wsb + off); off += 2048 * 4;
  int* base = (int*)(wsb + off); off += 2048 * 4;
  unsigned short* part = (unsigned short*)(wsb + off);
  size_t need = off + (size_t)T2 * 1024 * 2;            // +134 MB bf16 partials
  int use_part = (ws_size >= need) ? 1 : 0;

  float* out = (float*)d_out;

  if (!use_part)
    hipMemsetAsync(d_out, 0, (size_t)out_size * sizeof(float), stream);
  gate_kernel<<<T / 16, 256, 0, stream>>>(x, gw, xb, tok_e, tok_w);
  wconv_kernel<<<dim3(32, 32, 8), 256, 0, stream>>>(ew, wt);
  hist_kernel<<<T2 / 256, 256, 0, stream>>>(tok_e, tok_r, chunkhist);
  scan_kernel<<<1, 512, 0, stream>>>(chunkhist, base, ctrl);
  scatter_kernel<<<T2 / 256, 256, 0, stream>>>(tok_e, tok_r, tok_w, base,
                                               slot_token, slot_w);
  // up to 520 M-groups (128 rows) x 4 N-blocks (256 wide)
  moe_gemm<<<2080, 256, 0, stream>>>(xb, wt, eb, ctrl, slot_token, slot_w,
                                     part, out, T2, use_part);
  if (use_part)
    combine_kernel<<<T, 256, 0, stream>>>(part, out);
}